// Round 17
// baseline (237.937 us; speedup 1.0000x reference)
//
#include <hip/hip_runtime.h>
#include <hip/hip_fp16.h>
#include <math.h>

// BoundaryTransformerLayer: n=65536 pts, ns=16, C=64, CW=8.
// r16 base (212.7us). r17: NB_STAT 2048->4096 on the gather kernels
// (k_stats_w/k_u2/k_out2). 2048 = exactly 8 blocks/CU -> no refill queue,
// finish-skew drains CUs (occupancy read ~38%). 4096 gives 2x-deep queue;
// VGPR<=48 permits up to 10 resident blocks. Math untouched.

#define NB_STAT 4096

__device__ __forceinline__ float relu_(float v) { return v > 0.f ? v : 0.f; }

__device__ __forceinline__ unsigned pack_bf16(float a, float b) {
    unsigned ua = __float_as_uint(a);
    ua = (ua + 0x7FFFu + ((ua >> 16) & 1u)) >> 16;
    unsigned ub = __float_as_uint(b);
    ub = (ub + 0x7FFFu + ((ub >> 16) & 1u)) >> 16;
    return ua | (ub << 16);
}
__device__ __forceinline__ float ubf(unsigned u, int hi) {
    return __uint_as_float(hi ? (u & 0xFFFF0000u) : (u << 16));
}
__device__ __forceinline__ float ublo(unsigned u) { return __uint_as_float(u << 16); }
__device__ __forceinline__ float ubhi(unsigned u) { return __uint_as_float(u & 0xFFFF0000u); }

__device__ __forceinline__ unsigned pack_h2(float a, float b) {
    __half2 h = __floats2half2_rn(a, b);
    return *(unsigned*)&h;
}
__device__ __forceinline__ float h2lo(unsigned u) {
    __half2 h = *(__half2*)&u;
    return __low2float(h);
}
__device__ __forceinline__ float h2hi(unsigned u) {
    __half2 h = *(__half2*)&u;
    return __high2float(h);
}

// ---------------- K1: q/k/v projections (bf16 W in LDS) + fused t1-stats ----------------
__global__ __launch_bounds__(256) void k_proj5(
    const float* __restrict__ x,
    const float* __restrict__ Wq, const float* __restrict__ bq,
    const float* __restrict__ Wk, const float* __restrict__ bk,
    const float* __restrict__ Wv, const float* __restrict__ bv,
    unsigned* __restrict__ xqh, unsigned* __restrict__ xkh, unsigned* __restrict__ xvh,
    const float* __restrict__ p, const int* __restrict__ idx,
    const float* __restrict__ Wp1, const float* __restrict__ bp1,
    float* __restrict__ part1, int M)
{
    __shared__ uint2 wq2[1024], wk2[1024], wv2[1024];   // 3 x 8KB
    __shared__ float4 xs4[512];                          // [pt*16+kk] 8KB
    __shared__ float bqs[64], bks[64], bvs[64];
    __shared__ float red_p[4][6];
    int tid = threadIdx.x;
    for (int i = tid; i < 1024; i += 256) {
        int c = i & 63, kk = i >> 6;
        float4 q = ((const float4*)Wq)[c * 16 + kk];
        float4 k = ((const float4*)Wk)[c * 16 + kk];
        float4 v = ((const float4*)Wv)[c * 16 + kk];
        wq2[kk * 64 + c] = make_uint2(pack_bf16(q.x, q.y), pack_bf16(q.z, q.w));
        wk2[kk * 64 + c] = make_uint2(pack_bf16(k.x, k.y), pack_bf16(k.z, k.w));
        wv2[kk * 64 + c] = make_uint2(pack_bf16(v.x, v.y), pack_bf16(v.z, v.w));
    }
    if (tid < 64) { bqs[tid] = bq[tid]; bks[tid] = bk[tid]; bvs[tid] = bv[tid]; }
    size_t base = (size_t)blockIdx.x * 32;
    for (int i = tid; i < 512; i += 256)
        xs4[i] = ((const float4*)(x + base * 64))[i];
    __syncthreads();
    int c = tid & 63, w = tid >> 6;
    float aq[8], ak[8], av[8];
    #pragma unroll
    for (int pp = 0; pp < 8; ++pp) { aq[pp] = bqs[c]; ak[pp] = bks[c]; av[pp] = bvs[c]; }
    #pragma unroll 4
    for (int kk = 0; kk < 16; ++kk) {
        uint2 uq = wq2[kk * 64 + c];
        uint2 uk = wk2[kk * 64 + c];
        uint2 uv = wv2[kk * 64 + c];
        float q0 = ublo(uq.x), q1 = ubhi(uq.x), q2 = ublo(uq.y), q3 = ubhi(uq.y);
        float k0 = ublo(uk.x), k1 = ubhi(uk.x), k2 = ublo(uk.y), k3 = ubhi(uk.y);
        float v0 = ublo(uv.x), v1 = ubhi(uv.x), v2 = ublo(uv.y), v3 = ubhi(uv.y);
        #pragma unroll
        for (int pp = 0; pp < 8; ++pp) {
            float4 xv4 = xs4[(w * 8 + pp) * 16 + kk];   // wave-broadcast read
            aq[pp] = fmaf(xv4.x, q0, aq[pp]); aq[pp] = fmaf(xv4.y, q1, aq[pp]);
            aq[pp] = fmaf(xv4.z, q2, aq[pp]); aq[pp] = fmaf(xv4.w, q3, aq[pp]);
            ak[pp] = fmaf(xv4.x, k0, ak[pp]); ak[pp] = fmaf(xv4.y, k1, ak[pp]);
            ak[pp] = fmaf(xv4.z, k2, ak[pp]); ak[pp] = fmaf(xv4.w, k3, ak[pp]);
            av[pp] = fmaf(xv4.x, v0, av[pp]); av[pp] = fmaf(xv4.y, v1, av[pp]);
            av[pp] = fmaf(xv4.z, v2, av[pp]); av[pp] = fmaf(xv4.w, v3, av[pp]);
        }
    }
    #pragma unroll
    for (int pp = 0; pp < 8; ++pp) {
        size_t pt = base + w * 8 + pp;
        float hq = __shfl_down(aq[pp], 1, 64);
        float hk = __shfl_down(ak[pp], 1, 64);
        float hv = __shfl_down(av[pp], 1, 64);
        if ((c & 1) == 0) {
            xqh[pt * 32 + (c >> 1)] = pack_bf16(aq[pp], hq);
            xkh[pt * 32 + (c >> 1)] = pack_bf16(ak[pp], hk);
            xvh[pt * 32 + (c >> 1)] = pack_bf16(av[pp], hv);
        }
    }
    // ---- fused t1-stats (independent of projection results) ----
    float sw[9], sb[3];
    #pragma unroll
    for (int a = 0; a < 9; ++a) sw[a] = Wp1[a];
    #pragma unroll
    for (int a = 0; a < 3; ++a) sb[a] = bp1[a];
    float s0 = 0, s1 = 0, s2 = 0, q0 = 0, q1 = 0, q2 = 0;
    int step = gridDim.x * 256;
    for (int s = blockIdx.x * 256 + tid; s < M; s += step) {
        int i0 = s >> 4;
        int nb = idx[s];
        float g0 = p[nb * 3 + 0] - p[i0 * 3 + 0];
        float g1 = p[nb * 3 + 1] - p[i0 * 3 + 1];
        float g2 = p[nb * 3 + 2] - p[i0 * 3 + 2];
        float t0 = sb[0] + sw[0] * g0 + sw[1] * g1 + sw[2] * g2;
        float t1 = sb[1] + sw[3] * g0 + sw[4] * g1 + sw[5] * g2;
        float t2 = sb[2] + sw[6] * g0 + sw[7] * g1 + sw[8] * g2;
        s0 += t0; s1 += t1; s2 += t2;
        q0 = fmaf(t0, t0, q0); q1 = fmaf(t1, t1, q1); q2 = fmaf(t2, t2, q2);
    }
    float v6[6] = { s0, s1, s2, q0, q1, q2 };
    #pragma unroll
    for (int k = 0; k < 6; ++k) {
        float a = v6[k];
        for (int off = 32; off; off >>= 1) a += __shfl_down(a, off, 64);
        if ((tid & 63) == 0) red_p[tid >> 6][k] = a;
    }
    __syncthreads();
    if (tid < 6)
        part1[(size_t)blockIdx.x * 6 + tid] =
            red_p[0][tid] + red_p[1][tid] + red_p[2][tid] + red_p[3][tid];
}

// ---------------- finalize: parallel partial-sum reductions ----------------
__global__ __launch_bounds__(512) void k_fin_p(
    const float* __restrict__ part, int nbk, float invM,
    const float* __restrict__ g, const float* __restrict__ b,
    float* __restrict__ bnp)
{
    __shared__ float red[6][64];
    __shared__ float tot[6];
    int t = threadIdx.x;
    int col = t >> 6, stripe = t & 63;
    if (col < 6) {
        float a = 0.f;
        for (int k = stripe; k < nbk; k += 64)
            a += part[(size_t)k * 6 + col];
        red[col][stripe] = a;
    }
    __syncthreads();
    if (t < 6) {
        float a = 0.f;
        #pragma unroll
        for (int i = 0; i < 64; ++i) a += red[t][i];
        tot[t] = a;
    }
    __syncthreads();
    if (t < 3) {
        float mean = tot[t] * invM;
        float var = tot[3 + t] * invM - mean * mean;
        float sc = g[t] * rsqrtf(var + 1e-5f);
        bnp[t] = sc;
        bnp[3 + t] = b[t] - mean * sc;
    }
}

// k_fin_w0: bn_w0 finalize + materialize folded tables for k_u2.
__global__ __launch_bounds__(1024) void k_fin_w0(
    const float* __restrict__ part, int nbk, float invM,
    const float* __restrict__ g, const float* __restrict__ b,
    const float* __restrict__ Wp2, const float* __restrict__ bp2,
    const float* __restrict__ Ww1,
    float* __restrict__ out, float* __restrict__ tbl)
{
    __shared__ float red[8][128];
    __shared__ float tot[128];
    int t = threadIdx.x;
    int col = t & 127, stripe = t >> 7;
    float a0 = 0, a1 = 0, a2 = 0, a3 = 0;
    for (int k = stripe; k < nbk; k += 32) {
        a0 += part[(size_t)(k     ) * 128 + col];
        a1 += part[(size_t)(k +  8) * 128 + col];
        a2 += part[(size_t)(k + 16) * 128 + col];
        a3 += part[(size_t)(k + 24) * 128 + col];
    }
    red[stripe][col] = (a0 + a1) + (a2 + a3);
    if (t < 512) {
        int cc = t >> 5, q = (t >> 2) & 7, e = t & 3;
        tbl[320 + t] = Ww1[q * 64 + cc * 4 + e];
    }
    __syncthreads();
    if (t < 128) {
        float a = 0.f;
        #pragma unroll
        for (int i = 0; i < 8; ++i) a += red[i][t];
        tot[t] = a;
    }
    __syncthreads();
    if (t < 64) {
        float mean = tot[t] * invM;
        float var = tot[64 + t] * invM - mean * mean;
        float sc = g[t] * rsqrtf(var + 1e-5f);
        float sh = b[t] - mean * sc;
        out[t] = sc;
        out[64 + t] = sh;
        float wa = Wp2[t * 3 + 0], wb = Wp2[t * 3 + 1], wc = Wp2[t * 3 + 2], bc = bp2[t];
        tbl[t]       = sc;
        tbl[64 + t]  = sc * wa;
        tbl[128 + t] = sc * wb;
        tbl[192 + t] = sc * wc;
        tbl[256 + t] = sc * bc + sh;
    }
}

__global__ __launch_bounds__(1024) void k_fin_w1(
    const float* __restrict__ part, int nbk, float invM,
    const float* __restrict__ g, const float* __restrict__ b,
    float* __restrict__ out)
{
    __shared__ float red[64][16];
    __shared__ float tot[16];
    int t = threadIdx.x;
    int col = t & 15, stripe = t >> 4;
    float a = 0.f;
    for (int k = stripe; k < nbk; k += 64)
        a += part[(size_t)k * 16 + col];
    red[stripe][col] = a;
    __syncthreads();
    if (t < 16) {
        float s = 0.f;
        #pragma unroll
        for (int i = 0; i < 64; ++i) s += red[i][t];
        tot[t] = s;
    }
    __syncthreads();
    if (t < 8) {
        float mean = tot[t] * invM;
        float var = tot[8 + t] * invM - mean * mean;
        float sc = g[t] * rsqrtf(var + 1e-5f);
        out[t] = sc;
        out[8 + t] = b[t] - mean * sc;
    }
}

// ---------------- K3: stats of w_pre (scalar idx row, packed e shuffles) ----------------
__global__ __launch_bounds__(256) void k_stats_w(
    const float* __restrict__ p, const int* __restrict__ idx,
    const unsigned* __restrict__ xqh, const unsigned* __restrict__ xkh,
    const float* __restrict__ Wp1, const float* __restrict__ bp1,
    const float* __restrict__ bnp,
    const float* __restrict__ Wp2, const float* __restrict__ bp2,
    float* __restrict__ part, int n, int nwaves)
{
    int tid = threadIdx.x, lane = tid & 63;
    int wid = blockIdx.x * 4 + (tid >> 6);
    int sel = lane & 1;
    float wa = Wp2[lane * 3 + 0], wb = Wp2[lane * 3 + 1], wc = Wp2[lane * 3 + 2], bc = bp2[lane];
    float w10 = Wp1[0], w11 = Wp1[1], w12 = Wp1[2];
    float w13 = Wp1[3], w14 = Wp1[4], w15 = Wp1[5];
    float w16 = Wp1[6], w17 = Wp1[7], w18 = Wp1[8];
    float b10 = bp1[0], b11 = bp1[1], b12 = bp1[2];
    float sp0 = bnp[0], sp1 = bnp[1], sp2 = bnp[2];
    float hp0 = bnp[3], hp1 = bnp[4], hp2 = bnp[5];
    float sum = 0.f, sq = 0.f;
    for (int i = wid; i < n; i += nwaves) {
        const int* idxrow = idx + (size_t)i * 16;   // wave-uniform -> s_load
        float pix = p[i * 3 + 0], piy = p[i * 3 + 1], piz = p[i * 3 + 2];
        float e0 = 0.f, e1 = 0.f, e2 = 0.f;
        if (lane < 16) {
            int nb16 = idxrow[lane];
            float g0 = p[nb16 * 3 + 0] - pix;
            float g1 = p[nb16 * 3 + 1] - piy;
            float g2 = p[nb16 * 3 + 2] - piz;
            e0 = relu_((b10 + w10 * g0 + w11 * g1 + w12 * g2) * sp0 + hp0);
            e1 = relu_((b11 + w13 * g0 + w14 * g1 + w15 * g2) * sp1 + hp1);
            e2 = relu_((b12 + w16 * g0 + w17 * g1 + w18 * g2) * sp2 + hp2);
        }
        unsigned e01 = pack_h2(e0, e1);
        float xqc = ubf(xqh[(size_t)i * 32 + (lane >> 1)], sel);
        #pragma unroll
        for (int j = 0; j < 16; ++j) {
            int nb = idxrow[j];
            unsigned es = (unsigned)__shfl((int)e01, j, 64);
            float f2 = __shfl(e2, j, 64);
            float pr = bc + wa * h2lo(es) + wb * h2hi(es) + wc * f2;
            float kv = ubf(xkh[(size_t)nb * 32 + (lane >> 1)], sel);
            float w = kv - xqc + pr;
            sum += w;
            sq = fmaf(w, w, sq);
        }
    }
    __shared__ float red[4][2][64];
    red[tid >> 6][0][lane] = sum;
    red[tid >> 6][1][lane] = sq;
    __syncthreads();
    if (tid < 128) {
        int k = tid >> 6, c = tid & 63;
        part[(size_t)blockIdx.x * 128 + tid] =
            red[0][k][c] + red[1][k][c] + red[2][k][c] + red[3][k][c];
    }
}

// ---------------- K4: u = relu(bn_w0(w_pre)) @ Ww1.T + bw1, scalar tables ----------------
__global__ __launch_bounds__(256) void k_u2(
    const float* __restrict__ p, const int* __restrict__ idx,
    const unsigned* __restrict__ xqh, const unsigned* __restrict__ xkh,
    const float* __restrict__ Wp1, const float* __restrict__ bp1,
    const float* __restrict__ bnp,
    const float* __restrict__ tbl,
    const float* __restrict__ bw1,
    unsigned* __restrict__ uh, float* __restrict__ part, int M)
{
    const float4* S4 = (const float4*)(tbl);
    const float4* A4 = (const float4*)(tbl + 64);
    const float4* B4 = (const float4*)(tbl + 128);
    const float4* C4 = (const float4*)(tbl + 192);
    const float4* D4 = (const float4*)(tbl + 256);
    const float4* W4 = (const float4*)(tbl + 320);   // [cc*8+q]
    int tid = threadIdx.x;
    float w10 = Wp1[0], w11 = Wp1[1], w12 = Wp1[2];
    float w13 = Wp1[3], w14 = Wp1[4], w15 = Wp1[5];
    float w16 = Wp1[6], w17 = Wp1[7], w18 = Wp1[8];
    float b10 = bp1[0], b11 = bp1[1], b12 = bp1[2];
    float sp0 = bnp[0], sp1 = bnp[1], sp2 = bnp[2];
    float hp0 = bnp[3], hp1 = bnp[4], hp2 = bnp[5];
    float bw[8];
    #pragma unroll
    for (int q = 0; q < 8; ++q) bw[q] = bw1[q];
    float sum[8] = {0,0,0,0,0,0,0,0}, sq[8] = {0,0,0,0,0,0,0,0};
    int step = gridDim.x * 256;
    for (int s = blockIdx.x * 256 + tid; s < M; s += step) {
        int i0 = s >> 4;
        int nb = idx[s];
        float g0 = p[nb * 3 + 0] - p[i0 * 3 + 0];
        float g1 = p[nb * 3 + 1] - p[i0 * 3 + 1];
        float g2 = p[nb * 3 + 2] - p[i0 * 3 + 2];
        float e0 = relu_((b10 + w10 * g0 + w11 * g1 + w12 * g2) * sp0 + hp0);
        float e1 = relu_((b11 + w13 * g0 + w14 * g1 + w15 * g2) * sp1 + hp1);
        float e2 = relu_((b12 + w16 * g0 + w17 * g1 + w18 * g2) * sp2 + hp2);
        const uint2* krh = (const uint2*)(xkh + (size_t)nb * 32);
        const uint2* qrh = (const uint2*)(xqh + (size_t)i0 * 32);
        float acc[8];
        #pragma unroll
        for (int q = 0; q < 8; ++q) acc[q] = bw[q];
        #pragma unroll 4
        for (int cc = 0; cc < 16; ++cc) {
            uint2 uk = krh[cc], uq = qrh[cc];
            float d0 = ublo(uk.x) - ublo(uq.x);
            float d1 = ubhi(uk.x) - ubhi(uq.x);
            float d2 = ublo(uk.y) - ublo(uq.y);
            float d3 = ubhi(uk.y) - ubhi(uq.y);
            float4 A = A4[cc], B = B4[cc], C = C4[cc], D = D4[cc], S = S4[cc];
            float t0 = fmaf(A.x, e0, D.x); t0 = fmaf(B.x, e1, t0); t0 = fmaf(C.x, e2, t0);
            float h0 = relu_(fmaf(S.x, d0, t0));
            float t1 = fmaf(A.y, e0, D.y); t1 = fmaf(B.y, e1, t1); t1 = fmaf(C.y, e2, t1);
            float h1 = relu_(fmaf(S.y, d1, t1));
            float t2 = fmaf(A.z, e0, D.z); t2 = fmaf(B.z, e1, t2); t2 = fmaf(C.z, e2, t2);
            float h2 = relu_(fmaf(S.z, d2, t2));
            float t3 = fmaf(A.w, e0, D.w); t3 = fmaf(B.w, e1, t3); t3 = fmaf(C.w, e2, t3);
            float h3 = relu_(fmaf(S.w, d3, t3));
            #pragma unroll
            for (int q = 0; q < 8; ++q) {
                float4 ww = W4[cc * 8 + q];
                acc[q] = fmaf(ww.x, h0, acc[q]);
                acc[q] = fmaf(ww.y, h1, acc[q]);
                acc[q] = fmaf(ww.z, h2, acc[q]);
                acc[q] = fmaf(ww.w, h3, acc[q]);
            }
        }
        ((uint4*)(uh + (size_t)s * 4))[0] = make_uint4(
            pack_bf16(acc[0], acc[1]), pack_bf16(acc[2], acc[3]),
            pack_bf16(acc[4], acc[5]), pack_bf16(acc[6], acc[7]));
        #pragma unroll
        for (int q = 0; q < 8; ++q) {
            sum[q] += acc[q];
            sq[q] = fmaf(acc[q], acc[q], sq[q]);
        }
    }
    __shared__ float red4[4][16];
    #pragma unroll
    for (int q = 0; q < 8; ++q) {
        float v = sum[q];
        for (int off = 32; off; off >>= 1) v += __shfl_down(v, off, 64);
        if ((tid & 63) == 0) red4[tid >> 6][q] = v;
        v = sq[q];
        for (int off = 32; off; off >>= 1) v += __shfl_down(v, off, 64);
        if ((tid & 63) == 0) red4[tid >> 6][8 + q] = v;
    }
    __syncthreads();
    if (tid < 16)
        part[(size_t)blockIdx.x * 16 + tid] = red4[0][tid] + red4[1][tid] + red4[2][tid] + red4[3][tid];
}

// ---------------- K5: softmax + weighted sum (scalar idx, packed shuffles) ----------------
__global__ __launch_bounds__(256) void k_out2(
    const float* __restrict__ p, const int* __restrict__ idx,
    const unsigned* __restrict__ xvh, const unsigned* __restrict__ uh,
    const float* __restrict__ Wp1, const float* __restrict__ bp1,
    const float* __restrict__ bnp,
    const float* __restrict__ Wp2, const float* __restrict__ bp2,
    const float* __restrict__ bnw1,
    const float* __restrict__ Ww2, const float* __restrict__ bw2,
    float* __restrict__ out, int n, int nwaves)
{
    int tid = threadIdx.x, lane = tid & 63;
    int wid = blockIdx.x * 4 + (tid >> 6);
    int qq = lane & 7, sel = lane & 1, jg = lane >> 3;
    float wa = Wp2[lane * 3 + 0], wb = Wp2[lane * 3 + 1], wc = Wp2[lane * 3 + 2], bc = bp2[lane];
    float s1 = bnw1[qq], h1 = bnw1[8 + qq];
    float w2r[8];
    #pragma unroll
    for (int k = 0; k < 8; ++k) w2r[k] = Ww2[qq * 8 + k];
    float bz = bw2[qq];
    float w10 = Wp1[0], w11 = Wp1[1], w12 = Wp1[2];
    float w13 = Wp1[3], w14 = Wp1[4], w15 = Wp1[5];
    float w16 = Wp1[6], w17 = Wp1[7], w18 = Wp1[8];
    float b10 = bp1[0], b11 = bp1[1], b12 = bp1[2];
    float sp0 = bnp[0], sp1 = bnp[1], sp2 = bnp[2];
    float hp0 = bnp[3], hp1 = bnp[4], hp2 = bnp[5];
    for (int i = wid; i < n; i += nwaves) {
        const int* idxrow = idx + (size_t)i * 16;   // wave-uniform -> s_load
        float pix = p[i * 3 + 0], piy = p[i * 3 + 1], piz = p[i * 3 + 2];
        float e0 = 0.f, e1 = 0.f, e2 = 0.f;
        if (lane < 16) {
            int nb16 = idxrow[lane];
            float g0 = p[nb16 * 3 + 0] - pix;
            float g1 = p[nb16 * 3 + 1] - piy;
            float g2 = p[nb16 * 3 + 2] - piz;
            e0 = relu_((b10 + w10 * g0 + w11 * g1 + w12 * g2) * sp0 + hp0);
            e1 = relu_((b11 + w13 * g0 + w14 * g1 + w15 * g2) * sp1 + hp1);
            e2 = relu_((b12 + w16 * g0 + w17 * g1 + w18 * g2) * sp2 + hp2);
        }
        float u1 = ubf(uh[(size_t)i * 64 + (lane >> 1)], sel);
        float u2 = ubf(uh[(size_t)i * 64 + 32 + (lane >> 1)], sel);
        float r1 = relu_(fmaf(u1, s1, h1));
        float r2 = relu_(fmaf(u2, s1, h1));
        unsigned rr = pack_h2(r1, r2);
        int base = lane & 56;
        float z1 = bz, z2 = bz;
        #pragma unroll
        for (int k = 0; k < 8; ++k) {
            unsigned rs = (unsigned)__shfl((int)rr, base + k, 64);
            z1 = fmaf(w2r[k], h2lo(rs), z1);
            z2 = fmaf(w2r[k], h2hi(rs), z2);
        }
        float m = fmaxf(z1, z2);
        m = fmaxf(m, __shfl_xor(m, 8, 64));
        m = fmaxf(m, __shfl_xor(m, 16, 64));
        m = fmaxf(m, __shfl_xor(m, 32, 64));
        float p1 = __expf(z1 - m), p2 = __expf(z2 - m);
        float se = p1 + p2;
        se += __shfl_xor(se, 8, 64);
        se += __shfl_xor(se, 16, 64);
        se += __shfl_xor(se, 32, 64);
        float inv = 1.0f / se;
        float wt1 = p1 * inv, wt2 = p2 * inv;
        float f0a = __shfl(e0, jg, 64), f0b = __shfl(e0, 8 + jg, 64);
        float f1a = __shfl(e1, jg, 64), f1b = __shfl(e1, 8 + jg, 64);
        float f2a = __shfl(e2, jg, 64), f2b = __shfl(e2, 8 + jg, 64);
        float F0 = wt1 * f0a + wt2 * f0b;
        float F1 = wt1 * f1a + wt2 * f1b;
        float F2 = wt1 * f2a + wt2 * f2b;
        F0 += __shfl_xor(F0, 8, 64); F0 += __shfl_xor(F0, 16, 64); F0 += __shfl_xor(F0, 32, 64);
        F1 += __shfl_xor(F1, 8, 64); F1 += __shfl_xor(F1, 16, 64); F1 += __shfl_xor(F1, 32, 64);
        F2 += __shfl_xor(F2, 8, 64); F2 += __shfl_xor(F2, 16, 64); F2 += __shfl_xor(F2, 32, 64);
        float acc = bc + wa * F0 + wb * F1 + wc * F2;
        unsigned wtp = pack_h2(wt1, wt2);
        #pragma unroll
        for (int j = 0; j < 8; ++j) {
            int nbA = idxrow[j];
            int nbB = idxrow[j + 8];
            unsigned wp = (unsigned)__shfl((int)wtp, (j << 3) + qq, 64);
            float gvA = ubf(xvh[(size_t)nbA * 32 + (lane >> 1)], sel);
            float gvB = ubf(xvh[(size_t)nbB * 32 + (lane >> 1)], sel);
            acc = fmaf(gvA, h2lo(wp), acc);
            acc = fmaf(gvB, h2hi(wp), acc);
        }
        out[(size_t)i * 64 + lane] = acc;
    }
}

extern "C" void kernel_launch(void* const* d_in, const int* in_sizes, int n_in,
                              void* d_out, int out_size, void* d_ws, size_t ws_size,
                              hipStream_t stream) {
    const float* p    = (const float*)d_in[0];
    const float* x    = (const float*)d_in[1];
    const int*   idx  = (const int*)d_in[2];
    const float* Wq   = (const float*)d_in[3];
    const float* bq   = (const float*)d_in[4];
    const float* Wk   = (const float*)d_in[5];
    const float* bk   = (const float*)d_in[6];
    const float* Wv   = (const float*)d_in[7];
    const float* bv   = (const float*)d_in[8];
    const float* Wp1  = (const float*)d_in[9];
    const float* bp1  = (const float*)d_in[10];
    const float* bnpg = (const float*)d_in[11];
    const float* bnpb = (const float*)d_in[12];
    const float* Wp2  = (const float*)d_in[13];
    const float* bp2  = (const float*)d_in[14];
    const float* bn0g = (const float*)d_in[15];
    const float* bn0b = (const float*)d_in[16];
    const float* Ww1  = (const float*)d_in[17];
    const float* bw1  = (const float*)d_in[18];
    const float* bn1g = (const float*)d_in[19];
    const float* bn1b = (const float*)d_in[20];
    const float* Ww2  = (const float*)d_in[21];
    const float* bw2  = (const float*)d_in[22];

    int n = in_sizes[1] / 64;     // 65536
    int M = n * 16;               // n * ns
    float invM = 1.0f / (float)M;

    // workspace layout
    unsigned* xqh = (unsigned*)d_ws;                   // n*32
    unsigned* xkh = xqh + (size_t)n * 32;
    unsigned* xvh = xkh + (size_t)n * 32;
    unsigned* uh  = xvh + (size_t)n * 32;              // M*4
    float* part1 = (float*)(uh + (size_t)M * 4);       // 2048*6
    float* part2 = part1 + (size_t)2048 * 6;           // NB_STAT*128
    float* part3 = part2 + (size_t)NB_STAT * 128;      // NB_STAT*16
    float* bnp   = part3 + (size_t)NB_STAT * 16;       // 6 (pad 8)
    float* bnw0  = bnp + 8;                            // 128
    float* bnw1  = bnw0 + 128;                         // 16
    float* tbl   = bnw1 + 16;                          // 832 folded tables

    k_proj5<<<n / 32, 256, 0, stream>>>(x, Wq, bq, Wk, bk, Wv, bv, xqh, xkh, xvh,
                                        p, idx, Wp1, bp1, part1, M);
    k_fin_p<<<1, 512, 0, stream>>>(part1, n / 32, invM, bnpg, bnpb, bnp);
    k_stats_w<<<NB_STAT, 256, 0, stream>>>(p, idx, xqh, xkh, Wp1, bp1, bnp, Wp2, bp2, part2, n, NB_STAT * 4);
    k_fin_w0<<<1, 1024, 0, stream>>>(part2, NB_STAT, invM, bn0g, bn0b, Wp2, bp2, Ww1, bnw0, tbl);
    k_u2<<<NB_STAT, 256, 0, stream>>>(p, idx, xqh, xkh, Wp1, bp1, bnp, tbl, bw1, uh, part3, M);
    k_fin_w1<<<1, 1024, 0, stream>>>(part3, NB_STAT, invM, bn1g, bn1b, bnw1);
    k_out2<<<NB_STAT, 256, 0, stream>>>(p, idx, xvh, uh, Wp1, bp1, bnp, Wp2, bp2, bnw1, Ww2, bw2, (float*)d_out, n, NB_STAT * 4);
}

// Round 18
// 212.518 us; speedup vs baseline: 1.1196x; 1.1196x over previous
//
#include <hip/hip_runtime.h>
#include <hip/hip_fp16.h>
#include <math.h>

// BoundaryTransformerLayer: n=65536 pts, ns=16, C=64, CW=8.
// FINAL (r16 best, 212.7us): r17's 4096-block grid regressed (238us) ->
// reverted to 2048. Pipeline is within ~10% of the component-wise
// random-gather floor (~430MB of 128B scattered row requests @ ~2.5TB/s).

#define NB_STAT 2048

__device__ __forceinline__ float relu_(float v) { return v > 0.f ? v : 0.f; }

__device__ __forceinline__ unsigned pack_bf16(float a, float b) {
    unsigned ua = __float_as_uint(a);
    ua = (ua + 0x7FFFu + ((ua >> 16) & 1u)) >> 16;
    unsigned ub = __float_as_uint(b);
    ub = (ub + 0x7FFFu + ((ub >> 16) & 1u)) >> 16;
    return ua | (ub << 16);
}
__device__ __forceinline__ float ubf(unsigned u, int hi) {
    return __uint_as_float(hi ? (u & 0xFFFF0000u) : (u << 16));
}
__device__ __forceinline__ float ublo(unsigned u) { return __uint_as_float(u << 16); }
__device__ __forceinline__ float ubhi(unsigned u) { return __uint_as_float(u & 0xFFFF0000u); }

__device__ __forceinline__ unsigned pack_h2(float a, float b) {
    __half2 h = __floats2half2_rn(a, b);
    return *(unsigned*)&h;
}
__device__ __forceinline__ float h2lo(unsigned u) {
    __half2 h = *(__half2*)&u;
    return __low2float(h);
}
__device__ __forceinline__ float h2hi(unsigned u) {
    __half2 h = *(__half2*)&u;
    return __high2float(h);
}

// ---------------- K1: q/k/v projections (bf16 W in LDS) + fused t1-stats ----------------
__global__ __launch_bounds__(256) void k_proj5(
    const float* __restrict__ x,
    const float* __restrict__ Wq, const float* __restrict__ bq,
    const float* __restrict__ Wk, const float* __restrict__ bk,
    const float* __restrict__ Wv, const float* __restrict__ bv,
    unsigned* __restrict__ xqh, unsigned* __restrict__ xkh, unsigned* __restrict__ xvh,
    const float* __restrict__ p, const int* __restrict__ idx,
    const float* __restrict__ Wp1, const float* __restrict__ bp1,
    float* __restrict__ part1, int M)
{
    __shared__ uint2 wq2[1024], wk2[1024], wv2[1024];   // 3 x 8KB
    __shared__ float4 xs4[512];                          // [pt*16+kk] 8KB
    __shared__ float bqs[64], bks[64], bvs[64];
    __shared__ float red_p[4][6];
    int tid = threadIdx.x;
    for (int i = tid; i < 1024; i += 256) {
        int c = i & 63, kk = i >> 6;
        float4 q = ((const float4*)Wq)[c * 16 + kk];
        float4 k = ((const float4*)Wk)[c * 16 + kk];
        float4 v = ((const float4*)Wv)[c * 16 + kk];
        wq2[kk * 64 + c] = make_uint2(pack_bf16(q.x, q.y), pack_bf16(q.z, q.w));
        wk2[kk * 64 + c] = make_uint2(pack_bf16(k.x, k.y), pack_bf16(k.z, k.w));
        wv2[kk * 64 + c] = make_uint2(pack_bf16(v.x, v.y), pack_bf16(v.z, v.w));
    }
    if (tid < 64) { bqs[tid] = bq[tid]; bks[tid] = bk[tid]; bvs[tid] = bv[tid]; }
    size_t base = (size_t)blockIdx.x * 32;
    for (int i = tid; i < 512; i += 256)
        xs4[i] = ((const float4*)(x + base * 64))[i];
    __syncthreads();
    int c = tid & 63, w = tid >> 6;
    float aq[8], ak[8], av[8];
    #pragma unroll
    for (int pp = 0; pp < 8; ++pp) { aq[pp] = bqs[c]; ak[pp] = bks[c]; av[pp] = bvs[c]; }
    #pragma unroll 4
    for (int kk = 0; kk < 16; ++kk) {
        uint2 uq = wq2[kk * 64 + c];
        uint2 uk = wk2[kk * 64 + c];
        uint2 uv = wv2[kk * 64 + c];
        float q0 = ublo(uq.x), q1 = ubhi(uq.x), q2 = ublo(uq.y), q3 = ubhi(uq.y);
        float k0 = ublo(uk.x), k1 = ubhi(uk.x), k2 = ublo(uk.y), k3 = ubhi(uk.y);
        float v0 = ublo(uv.x), v1 = ubhi(uv.x), v2 = ublo(uv.y), v3 = ubhi(uv.y);
        #pragma unroll
        for (int pp = 0; pp < 8; ++pp) {
            float4 xv4 = xs4[(w * 8 + pp) * 16 + kk];   // wave-broadcast read
            aq[pp] = fmaf(xv4.x, q0, aq[pp]); aq[pp] = fmaf(xv4.y, q1, aq[pp]);
            aq[pp] = fmaf(xv4.z, q2, aq[pp]); aq[pp] = fmaf(xv4.w, q3, aq[pp]);
            ak[pp] = fmaf(xv4.x, k0, ak[pp]); ak[pp] = fmaf(xv4.y, k1, ak[pp]);
            ak[pp] = fmaf(xv4.z, k2, ak[pp]); ak[pp] = fmaf(xv4.w, k3, ak[pp]);
            av[pp] = fmaf(xv4.x, v0, av[pp]); av[pp] = fmaf(xv4.y, v1, av[pp]);
            av[pp] = fmaf(xv4.z, v2, av[pp]); av[pp] = fmaf(xv4.w, v3, av[pp]);
        }
    }
    #pragma unroll
    for (int pp = 0; pp < 8; ++pp) {
        size_t pt = base + w * 8 + pp;
        float hq = __shfl_down(aq[pp], 1, 64);
        float hk = __shfl_down(ak[pp], 1, 64);
        float hv = __shfl_down(av[pp], 1, 64);
        if ((c & 1) == 0) {
            xqh[pt * 32 + (c >> 1)] = pack_bf16(aq[pp], hq);
            xkh[pt * 32 + (c >> 1)] = pack_bf16(ak[pp], hk);
            xvh[pt * 32 + (c >> 1)] = pack_bf16(av[pp], hv);
        }
    }
    // ---- fused t1-stats (independent of projection results) ----
    float sw[9], sb[3];
    #pragma unroll
    for (int a = 0; a < 9; ++a) sw[a] = Wp1[a];
    #pragma unroll
    for (int a = 0; a < 3; ++a) sb[a] = bp1[a];
    float s0 = 0, s1 = 0, s2 = 0, q0 = 0, q1 = 0, q2 = 0;
    int step = gridDim.x * 256;
    for (int s = blockIdx.x * 256 + tid; s < M; s += step) {
        int i0 = s >> 4;
        int nb = idx[s];
        float g0 = p[nb * 3 + 0] - p[i0 * 3 + 0];
        float g1 = p[nb * 3 + 1] - p[i0 * 3 + 1];
        float g2 = p[nb * 3 + 2] - p[i0 * 3 + 2];
        float t0 = sb[0] + sw[0] * g0 + sw[1] * g1 + sw[2] * g2;
        float t1 = sb[1] + sw[3] * g0 + sw[4] * g1 + sw[5] * g2;
        float t2 = sb[2] + sw[6] * g0 + sw[7] * g1 + sw[8] * g2;
        s0 += t0; s1 += t1; s2 += t2;
        q0 = fmaf(t0, t0, q0); q1 = fmaf(t1, t1, q1); q2 = fmaf(t2, t2, q2);
    }
    float v6[6] = { s0, s1, s2, q0, q1, q2 };
    #pragma unroll
    for (int k = 0; k < 6; ++k) {
        float a = v6[k];
        for (int off = 32; off; off >>= 1) a += __shfl_down(a, off, 64);
        if ((tid & 63) == 0) red_p[tid >> 6][k] = a;
    }
    __syncthreads();
    if (tid < 6)
        part1[(size_t)blockIdx.x * 6 + tid] =
            red_p[0][tid] + red_p[1][tid] + red_p[2][tid] + red_p[3][tid];
}

// ---------------- finalize: parallel partial-sum reductions ----------------
__global__ __launch_bounds__(512) void k_fin_p(
    const float* __restrict__ part, int nbk, float invM,
    const float* __restrict__ g, const float* __restrict__ b,
    float* __restrict__ bnp)
{
    __shared__ float red[6][64];
    __shared__ float tot[6];
    int t = threadIdx.x;
    int col = t >> 6, stripe = t & 63;
    if (col < 6) {
        float a = 0.f;
        for (int k = stripe; k < nbk; k += 64)
            a += part[(size_t)k * 6 + col];
        red[col][stripe] = a;
    }
    __syncthreads();
    if (t < 6) {
        float a = 0.f;
        #pragma unroll
        for (int i = 0; i < 64; ++i) a += red[t][i];
        tot[t] = a;
    }
    __syncthreads();
    if (t < 3) {
        float mean = tot[t] * invM;
        float var = tot[3 + t] * invM - mean * mean;
        float sc = g[t] * rsqrtf(var + 1e-5f);
        bnp[t] = sc;
        bnp[3 + t] = b[t] - mean * sc;
    }
}

// k_fin_w0: bn_w0 finalize + materialize folded tables for k_u2.
__global__ __launch_bounds__(1024) void k_fin_w0(
    const float* __restrict__ part, int nbk, float invM,
    const float* __restrict__ g, const float* __restrict__ b,
    const float* __restrict__ Wp2, const float* __restrict__ bp2,
    const float* __restrict__ Ww1,
    float* __restrict__ out, float* __restrict__ tbl)
{
    __shared__ float red[8][128];
    __shared__ float tot[128];
    int t = threadIdx.x;
    int col = t & 127, stripe = t >> 7;
    float a0 = 0, a1 = 0, a2 = 0, a3 = 0;
    for (int k = stripe; k < nbk; k += 32) {
        a0 += part[(size_t)(k     ) * 128 + col];
        a1 += part[(size_t)(k +  8) * 128 + col];
        a2 += part[(size_t)(k + 16) * 128 + col];
        a3 += part[(size_t)(k + 24) * 128 + col];
    }
    red[stripe][col] = (a0 + a1) + (a2 + a3);
    if (t < 512) {
        int cc = t >> 5, q = (t >> 2) & 7, e = t & 3;
        tbl[320 + t] = Ww1[q * 64 + cc * 4 + e];
    }
    __syncthreads();
    if (t < 128) {
        float a = 0.f;
        #pragma unroll
        for (int i = 0; i < 8; ++i) a += red[i][t];
        tot[t] = a;
    }
    __syncthreads();
    if (t < 64) {
        float mean = tot[t] * invM;
        float var = tot[64 + t] * invM - mean * mean;
        float sc = g[t] * rsqrtf(var + 1e-5f);
        float sh = b[t] - mean * sc;
        out[t] = sc;
        out[64 + t] = sh;
        float wa = Wp2[t * 3 + 0], wb = Wp2[t * 3 + 1], wc = Wp2[t * 3 + 2], bc = bp2[t];
        tbl[t]       = sc;
        tbl[64 + t]  = sc * wa;
        tbl[128 + t] = sc * wb;
        tbl[192 + t] = sc * wc;
        tbl[256 + t] = sc * bc + sh;
    }
}

__global__ __launch_bounds__(1024) void k_fin_w1(
    const float* __restrict__ part, int nbk, float invM,
    const float* __restrict__ g, const float* __restrict__ b,
    float* __restrict__ out)
{
    __shared__ float red[64][16];
    __shared__ float tot[16];
    int t = threadIdx.x;
    int col = t & 15, stripe = t >> 4;
    float a = 0.f;
    for (int k = stripe; k < nbk; k += 64)
        a += part[(size_t)k * 16 + col];
    red[stripe][col] = a;
    __syncthreads();
    if (t < 16) {
        float s = 0.f;
        #pragma unroll
        for (int i = 0; i < 64; ++i) s += red[i][t];
        tot[t] = s;
    }
    __syncthreads();
    if (t < 8) {
        float mean = tot[t] * invM;
        float var = tot[8 + t] * invM - mean * mean;
        float sc = g[t] * rsqrtf(var + 1e-5f);
        out[t] = sc;
        out[8 + t] = b[t] - mean * sc;
    }
}

// ---------------- K3: stats of w_pre (scalar idx row, packed e shuffles) ----------------
__global__ __launch_bounds__(256) void k_stats_w(
    const float* __restrict__ p, const int* __restrict__ idx,
    const unsigned* __restrict__ xqh, const unsigned* __restrict__ xkh,
    const float* __restrict__ Wp1, const float* __restrict__ bp1,
    const float* __restrict__ bnp,
    const float* __restrict__ Wp2, const float* __restrict__ bp2,
    float* __restrict__ part, int n, int nwaves)
{
    int tid = threadIdx.x, lane = tid & 63;
    int wid = blockIdx.x * 4 + (tid >> 6);
    int sel = lane & 1;
    float wa = Wp2[lane * 3 + 0], wb = Wp2[lane * 3 + 1], wc = Wp2[lane * 3 + 2], bc = bp2[lane];
    float w10 = Wp1[0], w11 = Wp1[1], w12 = Wp1[2];
    float w13 = Wp1[3], w14 = Wp1[4], w15 = Wp1[5];
    float w16 = Wp1[6], w17 = Wp1[7], w18 = Wp1[8];
    float b10 = bp1[0], b11 = bp1[1], b12 = bp1[2];
    float sp0 = bnp[0], sp1 = bnp[1], sp2 = bnp[2];
    float hp0 = bnp[3], hp1 = bnp[4], hp2 = bnp[5];
    float sum = 0.f, sq = 0.f;
    for (int i = wid; i < n; i += nwaves) {
        const int* idxrow = idx + (size_t)i * 16;   // wave-uniform -> s_load
        float pix = p[i * 3 + 0], piy = p[i * 3 + 1], piz = p[i * 3 + 2];
        float e0 = 0.f, e1 = 0.f, e2 = 0.f;
        if (lane < 16) {
            int nb16 = idxrow[lane];
            float g0 = p[nb16 * 3 + 0] - pix;
            float g1 = p[nb16 * 3 + 1] - piy;
            float g2 = p[nb16 * 3 + 2] - piz;
            e0 = relu_((b10 + w10 * g0 + w11 * g1 + w12 * g2) * sp0 + hp0);
            e1 = relu_((b11 + w13 * g0 + w14 * g1 + w15 * g2) * sp1 + hp1);
            e2 = relu_((b12 + w16 * g0 + w17 * g1 + w18 * g2) * sp2 + hp2);
        }
        unsigned e01 = pack_h2(e0, e1);
        float xqc = ubf(xqh[(size_t)i * 32 + (lane >> 1)], sel);
        #pragma unroll
        for (int j = 0; j < 16; ++j) {
            int nb = idxrow[j];
            unsigned es = (unsigned)__shfl((int)e01, j, 64);
            float f2 = __shfl(e2, j, 64);
            float pr = bc + wa * h2lo(es) + wb * h2hi(es) + wc * f2;
            float kv = ubf(xkh[(size_t)nb * 32 + (lane >> 1)], sel);
            float w = kv - xqc + pr;
            sum += w;
            sq = fmaf(w, w, sq);
        }
    }
    __shared__ float red[4][2][64];
    red[tid >> 6][0][lane] = sum;
    red[tid >> 6][1][lane] = sq;
    __syncthreads();
    if (tid < 128) {
        int k = tid >> 6, c = tid & 63;
        part[(size_t)blockIdx.x * 128 + tid] =
            red[0][k][c] + red[1][k][c] + red[2][k][c] + red[3][k][c];
    }
}

// ---------------- K4: u = relu(bn_w0(w_pre)) @ Ww1.T + bw1, scalar tables ----------------
__global__ __launch_bounds__(256) void k_u2(
    const float* __restrict__ p, const int* __restrict__ idx,
    const unsigned* __restrict__ xqh, const unsigned* __restrict__ xkh,
    const float* __restrict__ Wp1, const float* __restrict__ bp1,
    const float* __restrict__ bnp,
    const float* __restrict__ tbl,
    const float* __restrict__ bw1,
    unsigned* __restrict__ uh, float* __restrict__ part, int M)
{
    const float4* S4 = (const float4*)(tbl);
    const float4* A4 = (const float4*)(tbl + 64);
    const float4* B4 = (const float4*)(tbl + 128);
    const float4* C4 = (const float4*)(tbl + 192);
    const float4* D4 = (const float4*)(tbl + 256);
    const float4* W4 = (const float4*)(tbl + 320);   // [cc*8+q]
    int tid = threadIdx.x;
    float w10 = Wp1[0], w11 = Wp1[1], w12 = Wp1[2];
    float w13 = Wp1[3], w14 = Wp1[4], w15 = Wp1[5];
    float w16 = Wp1[6], w17 = Wp1[7], w18 = Wp1[8];
    float b10 = bp1[0], b11 = bp1[1], b12 = bp1[2];
    float sp0 = bnp[0], sp1 = bnp[1], sp2 = bnp[2];
    float hp0 = bnp[3], hp1 = bnp[4], hp2 = bnp[5];
    float bw[8];
    #pragma unroll
    for (int q = 0; q < 8; ++q) bw[q] = bw1[q];
    float sum[8] = {0,0,0,0,0,0,0,0}, sq[8] = {0,0,0,0,0,0,0,0};
    int step = gridDim.x * 256;
    for (int s = blockIdx.x * 256 + tid; s < M; s += step) {
        int i0 = s >> 4;
        int nb = idx[s];
        float g0 = p[nb * 3 + 0] - p[i0 * 3 + 0];
        float g1 = p[nb * 3 + 1] - p[i0 * 3 + 1];
        float g2 = p[nb * 3 + 2] - p[i0 * 3 + 2];
        float e0 = relu_((b10 + w10 * g0 + w11 * g1 + w12 * g2) * sp0 + hp0);
        float e1 = relu_((b11 + w13 * g0 + w14 * g1 + w15 * g2) * sp1 + hp1);
        float e2 = relu_((b12 + w16 * g0 + w17 * g1 + w18 * g2) * sp2 + hp2);
        const uint2* krh = (const uint2*)(xkh + (size_t)nb * 32);
        const uint2* qrh = (const uint2*)(xqh + (size_t)i0 * 32);
        float acc[8];
        #pragma unroll
        for (int q = 0; q < 8; ++q) acc[q] = bw[q];
        #pragma unroll 4
        for (int cc = 0; cc < 16; ++cc) {
            uint2 uk = krh[cc], uq = qrh[cc];
            float d0 = ublo(uk.x) - ublo(uq.x);
            float d1 = ubhi(uk.x) - ubhi(uq.x);
            float d2 = ublo(uk.y) - ublo(uq.y);
            float d3 = ubhi(uk.y) - ubhi(uq.y);
            float4 A = A4[cc], B = B4[cc], C = C4[cc], D = D4[cc], S = S4[cc];
            float t0 = fmaf(A.x, e0, D.x); t0 = fmaf(B.x, e1, t0); t0 = fmaf(C.x, e2, t0);
            float h0 = relu_(fmaf(S.x, d0, t0));
            float t1 = fmaf(A.y, e0, D.y); t1 = fmaf(B.y, e1, t1); t1 = fmaf(C.y, e2, t1);
            float h1 = relu_(fmaf(S.y, d1, t1));
            float t2 = fmaf(A.z, e0, D.z); t2 = fmaf(B.z, e1, t2); t2 = fmaf(C.z, e2, t2);
            float h2 = relu_(fmaf(S.z, d2, t2));
            float t3 = fmaf(A.w, e0, D.w); t3 = fmaf(B.w, e1, t3); t3 = fmaf(C.w, e2, t3);
            float h3 = relu_(fmaf(S.w, d3, t3));
            #pragma unroll
            for (int q = 0; q < 8; ++q) {
                float4 ww = W4[cc * 8 + q];
                acc[q] = fmaf(ww.x, h0, acc[q]);
                acc[q] = fmaf(ww.y, h1, acc[q]);
                acc[q] = fmaf(ww.z, h2, acc[q]);
                acc[q] = fmaf(ww.w, h3, acc[q]);
            }
        }
        ((uint4*)(uh + (size_t)s * 4))[0] = make_uint4(
            pack_bf16(acc[0], acc[1]), pack_bf16(acc[2], acc[3]),
            pack_bf16(acc[4], acc[5]), pack_bf16(acc[6], acc[7]));
        #pragma unroll
        for (int q = 0; q < 8; ++q) {
            sum[q] += acc[q];
            sq[q] = fmaf(acc[q], acc[q], sq[q]);
        }
    }
    __shared__ float red4[4][16];
    #pragma unroll
    for (int q = 0; q < 8; ++q) {
        float v = sum[q];
        for (int off = 32; off; off >>= 1) v += __shfl_down(v, off, 64);
        if ((tid & 63) == 0) red4[tid >> 6][q] = v;
        v = sq[q];
        for (int off = 32; off; off >>= 1) v += __shfl_down(v, off, 64);
        if ((tid & 63) == 0) red4[tid >> 6][8 + q] = v;
    }
    __syncthreads();
    if (tid < 16)
        part[(size_t)blockIdx.x * 16 + tid] = red4[0][tid] + red4[1][tid] + red4[2][tid] + red4[3][tid];
}

// ---------------- K5: softmax + weighted sum (scalar idx, packed shuffles) ----------------
__global__ __launch_bounds__(256) void k_out2(
    const float* __restrict__ p, const int* __restrict__ idx,
    const unsigned* __restrict__ xvh, const unsigned* __restrict__ uh,
    const float* __restrict__ Wp1, const float* __restrict__ bp1,
    const float* __restrict__ bnp,
    const float* __restrict__ Wp2, const float* __restrict__ bp2,
    const float* __restrict__ bnw1,
    const float* __restrict__ Ww2, const float* __restrict__ bw2,
    float* __restrict__ out, int n, int nwaves)
{
    int tid = threadIdx.x, lane = tid & 63;
    int wid = blockIdx.x * 4 + (tid >> 6);
    int qq = lane & 7, sel = lane & 1, jg = lane >> 3;
    float wa = Wp2[lane * 3 + 0], wb = Wp2[lane * 3 + 1], wc = Wp2[lane * 3 + 2], bc = bp2[lane];
    float s1 = bnw1[qq], h1 = bnw1[8 + qq];
    float w2r[8];
    #pragma unroll
    for (int k = 0; k < 8; ++k) w2r[k] = Ww2[qq * 8 + k];
    float bz = bw2[qq];
    float w10 = Wp1[0], w11 = Wp1[1], w12 = Wp1[2];
    float w13 = Wp1[3], w14 = Wp1[4], w15 = Wp1[5];
    float w16 = Wp1[6], w17 = Wp1[7], w18 = Wp1[8];
    float b10 = bp1[0], b11 = bp1[1], b12 = bp1[2];
    float sp0 = bnp[0], sp1 = bnp[1], sp2 = bnp[2];
    float hp0 = bnp[3], hp1 = bnp[4], hp2 = bnp[5];
    for (int i = wid; i < n; i += nwaves) {
        const int* idxrow = idx + (size_t)i * 16;   // wave-uniform -> s_load
        float pix = p[i * 3 + 0], piy = p[i * 3 + 1], piz = p[i * 3 + 2];
        float e0 = 0.f, e1 = 0.f, e2 = 0.f;
        if (lane < 16) {
            int nb16 = idxrow[lane];
            float g0 = p[nb16 * 3 + 0] - pix;
            float g1 = p[nb16 * 3 + 1] - piy;
            float g2 = p[nb16 * 3 + 2] - piz;
            e0 = relu_((b10 + w10 * g0 + w11 * g1 + w12 * g2) * sp0 + hp0);
            e1 = relu_((b11 + w13 * g0 + w14 * g1 + w15 * g2) * sp1 + hp1);
            e2 = relu_((b12 + w16 * g0 + w17 * g1 + w18 * g2) * sp2 + hp2);
        }
        float u1 = ubf(uh[(size_t)i * 64 + (lane >> 1)], sel);
        float u2 = ubf(uh[(size_t)i * 64 + 32 + (lane >> 1)], sel);
        float r1 = relu_(fmaf(u1, s1, h1));
        float r2 = relu_(fmaf(u2, s1, h1));
        unsigned rr = pack_h2(r1, r2);
        int base = lane & 56;
        float z1 = bz, z2 = bz;
        #pragma unroll
        for (int k = 0; k < 8; ++k) {
            unsigned rs = (unsigned)__shfl((int)rr, base + k, 64);
            z1 = fmaf(w2r[k], h2lo(rs), z1);
            z2 = fmaf(w2r[k], h2hi(rs), z2);
        }
        float m = fmaxf(z1, z2);
        m = fmaxf(m, __shfl_xor(m, 8, 64));
        m = fmaxf(m, __shfl_xor(m, 16, 64));
        m = fmaxf(m, __shfl_xor(m, 32, 64));
        float p1 = __expf(z1 - m), p2 = __expf(z2 - m);
        float se = p1 + p2;
        se += __shfl_xor(se, 8, 64);
        se += __shfl_xor(se, 16, 64);
        se += __shfl_xor(se, 32, 64);
        float inv = 1.0f / se;
        float wt1 = p1 * inv, wt2 = p2 * inv;
        float f0a = __shfl(e0, jg, 64), f0b = __shfl(e0, 8 + jg, 64);
        float f1a = __shfl(e1, jg, 64), f1b = __shfl(e1, 8 + jg, 64);
        float f2a = __shfl(e2, jg, 64), f2b = __shfl(e2, 8 + jg, 64);
        float F0 = wt1 * f0a + wt2 * f0b;
        float F1 = wt1 * f1a + wt2 * f1b;
        float F2 = wt1 * f2a + wt2 * f2b;
        F0 += __shfl_xor(F0, 8, 64); F0 += __shfl_xor(F0, 16, 64); F0 += __shfl_xor(F0, 32, 64);
        F1 += __shfl_xor(F1, 8, 64); F1 += __shfl_xor(F1, 16, 64); F1 += __shfl_xor(F1, 32, 64);
        F2 += __shfl_xor(F2, 8, 64); F2 += __shfl_xor(F2, 16, 64); F2 += __shfl_xor(F2, 32, 64);
        float acc = bc + wa * F0 + wb * F1 + wc * F2;
        unsigned wtp = pack_h2(wt1, wt2);
        #pragma unroll
        for (int j = 0; j < 8; ++j) {
            int nbA = idxrow[j];
            int nbB = idxrow[j + 8];
            unsigned wp = (unsigned)__shfl((int)wtp, (j << 3) + qq, 64);
            float gvA = ubf(xvh[(size_t)nbA * 32 + (lane >> 1)], sel);
            float gvB = ubf(xvh[(size_t)nbB * 32 + (lane >> 1)], sel);
            acc = fmaf(gvA, h2lo(wp), acc);
            acc = fmaf(gvB, h2hi(wp), acc);
        }
        out[(size_t)i * 64 + lane] = acc;
    }
}

extern "C" void kernel_launch(void* const* d_in, const int* in_sizes, int n_in,
                              void* d_out, int out_size, void* d_ws, size_t ws_size,
                              hipStream_t stream) {
    const float* p    = (const float*)d_in[0];
    const float* x    = (const float*)d_in[1];
    const int*   idx  = (const int*)d_in[2];
    const float* Wq   = (const float*)d_in[3];
    const float* bq   = (const float*)d_in[4];
    const float* Wk   = (const float*)d_in[5];
    const float* bk   = (const float*)d_in[6];
    const float* Wv   = (const float*)d_in[7];
    const float* bv   = (const float*)d_in[8];
    const float* Wp1  = (const float*)d_in[9];
    const float* bp1  = (const float*)d_in[10];
    const float* bnpg = (const float*)d_in[11];
    const float* bnpb = (const float*)d_in[12];
    const float* Wp2  = (const float*)d_in[13];
    const float* bp2  = (const float*)d_in[14];
    const float* bn0g = (const float*)d_in[15];
    const float* bn0b = (const float*)d_in[16];
    const float* Ww1  = (const float*)d_in[17];
    const float* bw1  = (const float*)d_in[18];
    const float* bn1g = (const float*)d_in[19];
    const float* bn1b = (const float*)d_in[20];
    const float* Ww2  = (const float*)d_in[21];
    const float* bw2  = (const float*)d_in[22];

    int n = in_sizes[1] / 64;     // 65536
    int M = n * 16;               // n * ns
    float invM = 1.0f / (float)M;

    // workspace layout
    unsigned* xqh = (unsigned*)d_ws;                   // n*32
    unsigned* xkh = xqh + (size_t)n * 32;
    unsigned* xvh = xkh + (size_t)n * 32;
    unsigned* uh  = xvh + (size_t)n * 32;              // M*4
    float* part1 = (float*)(uh + (size_t)M * 4);       // NB_STAT*6
    float* part2 = part1 + (size_t)NB_STAT * 6;        // NB_STAT*128
    float* part3 = part2 + (size_t)NB_STAT * 128;      // NB_STAT*16
    float* bnp   = part3 + (size_t)NB_STAT * 16;       // 6 (pad 8)
    float* bnw0  = bnp + 8;                            // 128
    float* bnw1  = bnw0 + 128;                         // 16
    float* tbl   = bnw1 + 16;                          // 832 folded tables

    k_proj5<<<n / 32, 256, 0, stream>>>(x, Wq, bq, Wk, bk, Wv, bv, xqh, xkh, xvh,
                                        p, idx, Wp1, bp1, part1, M);
    k_fin_p<<<1, 512, 0, stream>>>(part1, n / 32, invM, bnpg, bnpb, bnp);
    k_stats_w<<<NB_STAT, 256, 0, stream>>>(p, idx, xqh, xkh, Wp1, bp1, bnp, Wp2, bp2, part2, n, NB_STAT * 4);
    k_fin_w0<<<1, 1024, 0, stream>>>(part2, NB_STAT, invM, bn0g, bn0b, Wp2, bp2, Ww1, bnw0, tbl);
    k_u2<<<NB_STAT, 256, 0, stream>>>(p, idx, xqh, xkh, Wp1, bp1, bnp, tbl, bw1, uh, part3, M);
    k_fin_w1<<<1, 1024, 0, stream>>>(part3, NB_STAT, invM, bn1g, bn1b, bnw1);
    k_out2<<<NB_STAT, 256, 0, stream>>>(p, idx, xvh, uh, Wp1, bp1, bnp, Wp2, bp2, bnw1, Ww2, bw2, (float*)d_out, n, NB_STAT * 4);
}